// Round 14
// baseline (77.758 us; speedup 1.0000x reference)
//
#include <hip/hip_runtime.h>
#include <hip/hip_bf16.h>
#include <cmath>

#define B_ROWS 2048
#define D_DIM 512
#define C_COLS 10572
#define WPAD 10624  // 83 * 128, zero-padded weight rows

#define BM 128
#define BN 128
#define BK 32
#define NSTEP (D_DIM / BK)  // 16

#define NC_BLOCKS ((B_ROWS + WPAD) / 4)  // 3168 normcast blocks
#define GT_BLOCKS (B_ROWS / 4)           // 512 gt-dot blocks

typedef __attribute__((ext_vector_type(8))) short short8;
typedef __attribute__((ext_vector_type(4))) float f32x4;

// byte-address XOR swizzle (involution: byte bits 7-9 -> bits 4-6)
__device__ __host__ inline int swz(int a) { return a ^ (((a >> 7) & 7) << 4); }

__device__ inline void load_lds16(const void* g, const void* l) {
    __builtin_amdgcn_global_load_lds(
        (const __attribute__((address_space(1))) unsigned int*)g,
        (__attribute__((address_space(3))) unsigned int*)l, 16, 0, 0);
}

// ---------------------------------------------------------------------------
// Merged prep kernel.
// Blocks [0, NC_BLOCKS): normalize + bf16 cast for feat & weights (one wave
//   per row; float4 loads, short8 stores; weight rows >= C_COLS zero-filled;
//   zeroes rowsum for feat rows).
// Blocks [NC_BLOCKS, NC_BLOCKS+GT_BLOCKS): exact f32 cos_gt dot products
//   (one wave per row) -> cge. Overlap the streaming pass; L2-hit on weights.
// ---------------------------------------------------------------------------
__global__ __launch_bounds__(256) void prep_kernel(
    const float* __restrict__ feat, const float* __restrict__ wts,
    const int* __restrict__ label,
    __hip_bfloat16* __restrict__ fhi, __hip_bfloat16* __restrict__ whi,
    float* __restrict__ rowsum, float* __restrict__ cge) {
    int wave = threadIdx.x >> 6;
    int lane = threadIdx.x & 63;

    if (blockIdx.x >= NC_BLOCKS) {
        // ---- gt-dot role ----
        int row = (blockIdx.x - NC_BLOCKS) * 4 + wave;
        int lbl = label[row];
        const float4* f4 = (const float4*)(feat + (size_t)row * D_DIM);
        const float4* w4 = (const float4*)(wts + (size_t)lbl * D_DIM);
        float ff = 0.f, ww = 0.f, fw = 0.f;
#pragma unroll
        for (int i = 0; i < 2; ++i) {
            float4 a = f4[lane + i * 64];
            float4 b = w4[lane + i * 64];
            ff += a.x * a.x + a.y * a.y + a.z * a.z + a.w * a.w;
            ww += b.x * b.x + b.y * b.y + b.z * b.z + b.w * b.w;
            fw += a.x * b.x + a.y * b.y + a.z * b.z + a.w * b.w;
        }
#pragma unroll
        for (int off = 32; off > 0; off >>= 1) {
            ff += __shfl_xor(ff, off);
            ww += __shfl_xor(ww, off);
            fw += __shfl_xor(fw, off);
        }
        if (lane == 0) cge[row] = fw / (sqrtf(ff) * sqrtf(ww));
        return;
    }

    // ---- normcast role ----
    int idx = blockIdx.x * 4 + wave;
    const float* src;
    __hip_bfloat16* dst;
    if (idx < B_ROWS) {
        src = feat + (size_t)idx * D_DIM;
        dst = fhi + (size_t)idx * D_DIM;
        if (lane == 0) rowsum[idx] = 0.0f;
    } else {
        int r = idx - B_ROWS;
        dst = whi + (size_t)r * D_DIM;
        if (r >= C_COLS) {
            short8 z = {0, 0, 0, 0, 0, 0, 0, 0};
            *(short8*)(dst + lane * 8) = z;
            return;
        }
        src = wts + (size_t)r * D_DIM;
    }
    float4 a = *(const float4*)(src + lane * 8);
    float4 b = *(const float4*)(src + lane * 8 + 4);
    float ss = a.x * a.x + a.y * a.y + a.z * a.z + a.w * a.w +
               b.x * b.x + b.y * b.y + b.z * b.z + b.w * b.w;
#pragma unroll
    for (int off = 32; off > 0; off >>= 1) ss += __shfl_xor(ss, off);
    float rn = 1.0f / sqrtf(ss);
    float v[8] = {a.x * rn, a.y * rn, a.z * rn, a.w * rn,
                  b.x * rn, b.y * rn, b.z * rn, b.w * rn};
    short8 o;
#pragma unroll
    for (int k = 0; k < 8; ++k) {
        __hip_bfloat16 h = __float2bfloat16(v[k]);
        o[k] = *reinterpret_cast<short*>(&h);
    }
    *(short8*)(dst + lane * 8) = o;
}

// ---------------------------------------------------------------------------
// bf16 MFMA GEMM (R10 K-loop, locked): cos = A @ W^T. 128x128 tile, BK=32,
// 4 waves (2x2), each wave 64x64 = 4x4 x mfma_16x16x32. Triple-buffered LDS,
// prefetch-distance-2, counted s_waitcnt vmcnt(4) + raw s_barrier.
// Epilogue v2 (this round): LDS transpose, then per half: (1) bulk LDS->reg,
// (2) 16 back-to-back float4 stores (max store-issue density, all in flight),
// (3) exp/shuffle/atomic pass from registers while stores drain.
// ---------------------------------------------------------------------------
__global__ __launch_bounds__(256) void gemm_bf16_kernel(
    const __hip_bfloat16* __restrict__ fhi, const __hip_bfloat16* __restrict__ whi,
    float* __restrict__ cosm, float* __restrict__ logits, float* __restrict__ rowsum,
    float scale) {
    __shared__ __align__(16) char smem[49152];  // 3x(A 8KB) + 3x(B 8KB)

    int tid = threadIdx.x;
    int lane = tid & 63;
    int w = tid >> 6;
    int wr = w >> 1, wc = w & 1;

    // XCD chunking (8 chunks of 166) + column-major walk within chunk.
    int orig = blockIdx.y * gridDim.x + blockIdx.x;
    int s = (orig & 7) * 166 + (orig >> 3);  // nwg = 1328 = 8*166, bijective
    int by = s & 15;
    int bx = s >> 4;
    int row0 = by * BM;
    int col0 = bx * BN;

    // staging: LDS linear dest byte o -> global element at swz(o)
    int grow[2], gcol[2], ldsw[2];
#pragma unroll
    for (int i = 0; i < 2; ++i) {
        int o = i * 4096 + tid * 16;
        int q = swz(o);
        grow[i] = q >> 6;
        gcol[i] = (q & 63) >> 1;
        ldsw[i] = i * 4096 + w * 1024;
    }

    // fragment ds_read offsets (swizzled), fixed across K-steps
    int r = lane & 15, kb = lane >> 4;
    int aoff[4], boff[4];
#pragma unroll
    for (int m = 0; m < 4; ++m) {
        aoff[m] = swz((wr * 64 + m * 16 + r) * 64 + kb * 16);
        boff[m] = swz((wc * 64 + m * 16 + r) * 64 + kb * 16);
    }

    const __hip_bfloat16* Ap = fhi + (size_t)row0 * D_DIM;
    const __hip_bfloat16* Bp = whi + (size_t)col0 * D_DIM;

    auto stage = [&](int k0, int b) {
#pragma unroll
        for (int i = 0; i < 2; ++i) {
            size_t go = (size_t)grow[i] * D_DIM + k0 + gcol[i];
            load_lds16(Ap + go, smem + b * 8192 + ldsw[i]);
            load_lds16(Bp + go, smem + 24576 + b * 8192 + ldsw[i]);
        }
    };

    f32x4 acc[4][4] = {};

    stage(0, 0);
    stage(BK, 1);
    asm volatile("s_waitcnt vmcnt(4)" ::: "memory");
    __builtin_amdgcn_s_barrier();
    __builtin_amdgcn_sched_barrier(0);

    int cur = 0, sb = 2;
    for (int t = 0; t < NSTEP; ++t) {
        if (t + 2 < NSTEP) stage((t + 2) * BK, sb);
        const char* Ab = smem + cur * 8192;
        const char* Bb = smem + 24576 + cur * 8192;
        short8 af[4], bf[4];
#pragma unroll
        for (int m = 0; m < 4; ++m) af[m] = *(const short8*)(Ab + aoff[m]);
#pragma unroll
        for (int n = 0; n < 4; ++n) bf[n] = *(const short8*)(Bb + boff[n]);
        __builtin_amdgcn_s_setprio(1);
#pragma unroll
        for (int m = 0; m < 4; ++m)
#pragma unroll
            for (int n = 0; n < 4; ++n)
                acc[m][n] = __builtin_amdgcn_mfma_f32_16x16x32_bf16(af[m], bf[n],
                                                                    acc[m][n], 0, 0, 0);
        __builtin_amdgcn_s_setprio(0);
        if (t + 2 < NSTEP)
            asm volatile("s_waitcnt vmcnt(4)" ::: "memory");
        else
            asm volatile("s_waitcnt vmcnt(0)" ::: "memory");
        __builtin_amdgcn_s_barrier();
        __builtin_amdgcn_sched_barrier(0);
        cur = (cur == 2) ? 0 : cur + 1;
        sb = (sb == 2) ? 0 : sb + 1;
    }

    // ---- epilogue v2: transpose + store-burst + deferred exp pass ---------
    // C/D frag layout: row = wr*64 + m*16 + (lane>>4)*4 + j,
    //                  col = wc*64 + n*16 + (lane&15).
    float* tl = (float*)smem;
    const int LROW = 132;  // floats; 528B stride: 16B-aligned, 4-bank row shift
    int trow8 = tid >> 5;  // 0..7
    int c4 = tid & 31;     // float4 index within the 128-col tile
    bool cvalid = (col0 + c4 * 4) < C_COLS;  // boundary (76 cols) is 4-aligned

#pragma unroll
    for (int half = 0; half < 2; ++half) {
        if (wr == half) {
#pragma unroll
            for (int m = 0; m < 4; ++m)
#pragma unroll
                for (int n = 0; n < 4; ++n) {
                    int lc = wc * 64 + n * 16 + (lane & 15);
#pragma unroll
                    for (int j = 0; j < 4; ++j) {
                        int lr = m * 16 + (lane >> 4) * 4 + j;
                        tl[lr * LROW + lc] = acc[m][n][j];
                    }
                }
        }
        __syncthreads();

        // (1) bulk LDS -> registers
        float4 vv[8];
#pragma unroll
        for (int it = 0; it < 8; ++it)
            vv[it] = *(const float4*)&tl[(it * 8 + trow8) * LROW + c4 * 4];

        // (2) 16 back-to-back stores, no intervening dependency chains
        if (cvalid) {
            size_t cb = (size_t)(row0 + half * 64 + trow8) * C_COLS + col0 + c4 * 4;
#pragma unroll
            for (int it = 0; it < 8; ++it) {
                size_t o = cb + (size_t)(it * 8) * C_COLS;
                *(float4*)&cosm[o] = vv[it];
                float4 lg = make_float4(scale * vv[it].x, scale * vv[it].y,
                                        scale * vv[it].z, scale * vv[it].w);
                *(float4*)&logits[o] = lg;
            }
        }

        // (3) exp row-sums from register copies while stores drain
#pragma unroll
        for (int it = 0; it < 8; ++it) {
            float se = 0.f;
            if (cvalid) {
                se = __expf(scale * vv[it].x) + __expf(scale * vv[it].y) +
                     __expf(scale * vv[it].z) + __expf(scale * vv[it].w);
            }
#pragma unroll
            for (int off = 1; off < 32; off <<= 1) se += __shfl_xor(se, off);
            if (c4 == 0) atomicAdd(&rowsum[row0 + half * 64 + it * 8 + trow8], se);
        }
        __syncthreads();
    }
}

// ---------------------------------------------------------------------------
// gt patch + final scalar reductions, one block of 256.
// Uses exact cg from prep (cge), rowsum from the GEMM. Patches the gt column
// of cos/logits via the cancellation-free identity pi/(2θ)-1 = asin/acos.
// ---------------------------------------------------------------------------
__global__ __launch_bounds__(256) void gt_finalize_kernel(
    const int* __restrict__ label, const float* __restrict__ rowsum,
    const float* __restrict__ cge, float* __restrict__ cosm,
    float* __restrict__ logits, float* __restrict__ tail, float scale) {
    int tid = threadIdx.x;
    const float PI = 3.14159265358979323846f;
    float s = 0.f, mn = 1e30f, mx = -1e30f, sb = 0.f;
    for (int row = tid; row < B_ROWS; row += 256) {
        int lbl = label[row];
        float cg = cge[row];
        float S = rowsum[row];
        float e = expf(scale * cg);
        float p = e / S;
        float Bv = S - e;  // == exp(logit_gt)*(1/p - 1) exactly
        float marg;
        if (cg > 0.f) {
            marg = asinf(cg) / acosf(cg);  // == pi/(2*theta)-1, no cancellation
        } else {
            float dth = 0.5f * PI - 0.01f;
            marg = PI / (2.0f * dth) - 1.0f;
        }
        size_t o = (size_t)row * C_COLS + lbl;
        cosm[o] = cg;
        logits[o] = logf(Bv * marg);
        s += p;
        mn = fminf(mn, p);
        mx = fmaxf(mx, p);
        sb += Bv;
    }
#pragma unroll
    for (int off = 32; off > 0; off >>= 1) {
        s += __shfl_down(s, off);
        mn = fminf(mn, __shfl_down(mn, off));
        mx = fmaxf(mx, __shfl_down(mx, off));
        sb += __shfl_down(sb, off);
    }
    __shared__ float rs[4], rmn[4], rmx[4], rsb[4];
    int wave = tid >> 6;
    if ((tid & 63) == 0) { rs[wave] = s; rmn[wave] = mn; rmx[wave] = mx; rsb[wave] = sb; }
    __syncthreads();
    if (tid == 0) {
        float S = 0.f, MN = 1e30f, MX = -1e30f, SB = 0.f;
        for (int ww = 0; ww < 4; ++ww) {
            S += rs[ww]; MN = fminf(MN, rmn[ww]); MX = fmaxf(MX, rmx[ww]); SB += rsb[ww];
        }
        tail[0] = S / (float)B_ROWS;
        tail[1] = MN;
        tail[2] = MX;
        float meanB = SB / (float)B_ROWS;
        tail[3] = acosf(logf(meanB / (float)(C_COLS - 1)) / scale) / PI * 180.0f;
        tail[4] = 0.0f;
        tail[5] = 0.0f;
    }
}

// ---------------------------------------------------------------------------
extern "C" void kernel_launch(void* const* d_in, const int* in_sizes, int n_in,
                              void* d_out, int out_size, void* d_ws, size_t ws_size,
                              hipStream_t stream) {
    const float* feat = (const float*)d_in[0];
    const int* label = (const int*)d_in[1];
    const float* weights = (const float*)d_in[2];

    float* out = (float*)d_out;
    float* cos_out = out;
    float* logits_out = out + (size_t)B_ROWS * C_COLS;
    float* tail = out + (size_t)2 * B_ROWS * C_COLS;

    double scale_d = std::sqrt(2.0) * std::log((double)(C_COLS - 1));
    float scale = (float)scale_d;

    const size_t fsz = (size_t)B_ROWS * D_DIM * sizeof(__hip_bfloat16);  // 2 MB
    const size_t wsz = (size_t)WPAD * D_DIM * sizeof(__hip_bfloat16);    // 10.875 MB
    char* wsb = (char*)d_ws;
    __hip_bfloat16* fhi = (__hip_bfloat16*)wsb;
    __hip_bfloat16* whi = (__hip_bfloat16*)(wsb + fsz);
    float* rowsum = (float*)(wsb + fsz + wsz);
    float* cge = rowsum + B_ROWS;

    prep_kernel<<<NC_BLOCKS + GT_BLOCKS, 256, 0, stream>>>(feat, weights, label, fhi,
                                                           whi, rowsum, cge);

    dim3 grid(WPAD / BN, B_ROWS / BM);  // 83 x 16 = 1328
    gemm_bf16_kernel<<<grid, 256, 0, stream>>>(fhi, whi, cos_out, logits_out, rowsum,
                                               scale);

    gt_finalize_kernel<<<1, 256, 0, stream>>>(label, rowsum, cge, cos_out, logits_out,
                                              tail, scale);
}

// Round 15
// 72.250 us; speedup vs baseline: 1.0762x; 1.0762x over previous
//
#include <hip/hip_runtime.h>
#include <hip/hip_bf16.h>
#include <cmath>

#define B_ROWS 2048
#define D_DIM 512
#define C_COLS 10572
#define WPAD 10624  // 83 * 128, zero-padded weight rows

#define BM 128
#define BN 128
#define BK 32
#define NSTEP (D_DIM / BK)  // 16

typedef __attribute__((ext_vector_type(8))) short short8;
typedef __attribute__((ext_vector_type(4))) float f32x4;

// byte-address XOR swizzle (involution: byte bits 7-9 -> bits 4-6)
__device__ __host__ inline int swz(int a) { return a ^ (((a >> 7) & 7) << 4); }

__device__ inline void load_lds16(const void* g, const void* l) {
    __builtin_amdgcn_global_load_lds(
        (const __attribute__((address_space(1))) unsigned int*)g,
        (__attribute__((address_space(3))) unsigned int*)l, 16, 0, 0);
}

// ---------------------------------------------------------------------------
// Fused normalize + bf16 cast for BOTH matrices. One wave per row, 4 rows
// per block. float4 loads, short8 (16B) stores. Rows >= C_COLS in the weight
// range are zero-filled. Zeroes rowsum for feat rows.
// ---------------------------------------------------------------------------
__global__ __launch_bounds__(256) void normcast_kernel(
    const float* __restrict__ feat, const float* __restrict__ wts,
    __hip_bfloat16* __restrict__ fhi, __hip_bfloat16* __restrict__ whi,
    float* __restrict__ rowsum) {
    int idx = blockIdx.x * 4 + (threadIdx.x >> 6);
    int lane = threadIdx.x & 63;
    const float* src;
    __hip_bfloat16* dst;
    if (idx < B_ROWS) {
        src = feat + (size_t)idx * D_DIM;
        dst = fhi + (size_t)idx * D_DIM;
        if (lane == 0) rowsum[idx] = 0.0f;
    } else {
        int r = idx - B_ROWS;
        dst = whi + (size_t)r * D_DIM;
        if (r >= C_COLS) {
            short8 z = {0, 0, 0, 0, 0, 0, 0, 0};
            *(short8*)(dst + lane * 8) = z;
            return;
        }
        src = wts + (size_t)r * D_DIM;
    }
    float4 a = *(const float4*)(src + lane * 8);
    float4 b = *(const float4*)(src + lane * 8 + 4);
    float ss = a.x * a.x + a.y * a.y + a.z * a.z + a.w * a.w +
               b.x * b.x + b.y * b.y + b.z * b.z + b.w * b.w;
#pragma unroll
    for (int off = 32; off > 0; off >>= 1) ss += __shfl_xor(ss, off);
    float rn = 1.0f / sqrtf(ss);
    float v[8] = {a.x * rn, a.y * rn, a.z * rn, a.w * rn,
                  b.x * rn, b.y * rn, b.z * rn, b.w * rn};
    short8 o;
#pragma unroll
    for (int k = 0; k < 8; ++k) {
        __hip_bfloat16 h = __float2bfloat16(v[k]);
        o[k] = *reinterpret_cast<short*>(&h);
    }
    *(short8*)(dst + lane * 8) = o;
}

// ---------------------------------------------------------------------------
// bf16 MFMA GEMM (best-known R10 form, locked): cos = A @ W^T. 128x128 tile,
// BK=32, 4 waves (2x2), each wave 64x64 = 4x4 x mfma_16x16x32.
// Triple-buffered LDS, prefetch-distance-2 pipeline with counted
// s_waitcnt vmcnt(4) + raw s_barrier. LDS XOR-swizzled staging.
// Epilogue: LDS transpose -> coalesced float4 stores (lanes 0-31 = one row's
// 128 cols contiguous, 512B/row-group) + per-iteration exp rowsum
// (5 xor-shuffles per 32-lane group + 1 atomic per row).
// ---------------------------------------------------------------------------
__global__ __launch_bounds__(256) void gemm_bf16_kernel(
    const __hip_bfloat16* __restrict__ fhi, const __hip_bfloat16* __restrict__ whi,
    float* __restrict__ cosm, float* __restrict__ logits, float* __restrict__ rowsum,
    float scale) {
    __shared__ __align__(16) char smem[49152];  // 3x(A 8KB) + 3x(B 8KB)

    int tid = threadIdx.x;
    int lane = tid & 63;
    int w = tid >> 6;
    int wr = w >> 1, wc = w & 1;

    // XCD chunking (8 chunks of 166) + column-major walk within chunk:
    // 16 consecutive blocks share one W-panel (L2 reuse); fhi stays L2-resident.
    int orig = blockIdx.y * gridDim.x + blockIdx.x;
    int s = (orig & 7) * 166 + (orig >> 3);  // nwg = 1328 = 8*166, bijective
    int by = s & 15;   // 0..15
    int bx = s >> 4;   // 0..82
    int row0 = by * BM;
    int col0 = bx * BN;

    // staging: LDS linear dest byte o -> global element at swz(o)
    int grow[2], gcol[2], ldsw[2];
#pragma unroll
    for (int i = 0; i < 2; ++i) {
        int o = i * 4096 + tid * 16;
        int q = swz(o);
        grow[i] = q >> 6;          // tile row
        gcol[i] = (q & 63) >> 1;   // element within 32-wide k
        ldsw[i] = i * 4096 + w * 1024;  // wave-uniform LDS base
    }

    // fragment ds_read offsets (swizzled), fixed across K-steps
    int r = lane & 15, kb = lane >> 4;
    int aoff[4], boff[4];
#pragma unroll
    for (int m = 0; m < 4; ++m) {
        aoff[m] = swz((wr * 64 + m * 16 + r) * 64 + kb * 16);
        boff[m] = swz((wc * 64 + m * 16 + r) * 64 + kb * 16);
    }

    const __hip_bfloat16* Ap = fhi + (size_t)row0 * D_DIM;
    const __hip_bfloat16* Bp = whi + (size_t)col0 * D_DIM;

    auto stage = [&](int k0, int b) {
#pragma unroll
        for (int i = 0; i < 2; ++i) {
            size_t go = (size_t)grow[i] * D_DIM + k0 + gcol[i];
            load_lds16(Ap + go, smem + b * 8192 + ldsw[i]);
            load_lds16(Bp + go, smem + 24576 + b * 8192 + ldsw[i]);
        }
    };

    f32x4 acc[4][4] = {};

    // prologue: stage K-steps 0 and 1; wait only for step 0 (4 newest in flight)
    stage(0, 0);
    stage(BK, 1);
    asm volatile("s_waitcnt vmcnt(4)" ::: "memory");
    __builtin_amdgcn_s_barrier();
    __builtin_amdgcn_sched_barrier(0);

    int cur = 0, sb = 2;
    for (int t = 0; t < NSTEP; ++t) {
        if (t + 2 < NSTEP) stage((t + 2) * BK, sb);
        const char* Ab = smem + cur * 8192;
        const char* Bb = smem + 24576 + cur * 8192;
        short8 af[4], bf[4];
#pragma unroll
        for (int m = 0; m < 4; ++m) af[m] = *(const short8*)(Ab + aoff[m]);
#pragma unroll
        for (int n = 0; n < 4; ++n) bf[n] = *(const short8*)(Bb + boff[n]);
        __builtin_amdgcn_s_setprio(1);
#pragma unroll
        for (int m = 0; m < 4; ++m)
#pragma unroll
            for (int n = 0; n < 4; ++n)
                acc[m][n] = __builtin_amdgcn_mfma_f32_16x16x32_bf16(af[m], bf[n],
                                                                    acc[m][n], 0, 0, 0);
        __builtin_amdgcn_s_setprio(0);
        // counted wait: leave the 4 just-issued (t+2) loads in flight;
        // the (t+1) buffer's 4 older loads must have landed.
        if (t + 2 < NSTEP)
            asm volatile("s_waitcnt vmcnt(4)" ::: "memory");
        else
            asm volatile("s_waitcnt vmcnt(0)" ::: "memory");
        __builtin_amdgcn_s_barrier();
        __builtin_amdgcn_sched_barrier(0);
        cur = (cur == 2) ? 0 : cur + 1;
        sb = (sb == 2) ? 0 : sb + 1;
    }

    // ---- epilogue: LDS transpose -> coalesced float4 stores ---------------
    // C/D frag layout: row = wr*64 + m*16 + (lane>>4)*4 + j,
    //                  col = wc*64 + n*16 + (lane&15).
    // Mapping: lanes 0-31 = one row (32 float4s, 512B contiguous),
    // lanes 32-63 = next row; 8 iterations cover the 64-row half.
    float* tl = (float*)smem;
    const int LROW = 132;  // floats; 528B stride: 16B-aligned, 4-bank row shift
    int trow8 = tid >> 5;  // 0..7
    int c4 = tid & 31;     // float4 index within the 128-col tile
    bool cvalid = (col0 + c4 * 4) < C_COLS;  // boundary (76 cols) is 4-aligned

#pragma unroll
    for (int half = 0; half < 2; ++half) {
        if (wr == half) {
#pragma unroll
            for (int m = 0; m < 4; ++m)
#pragma unroll
                for (int n = 0; n < 4; ++n) {
                    int lc = wc * 64 + n * 16 + (lane & 15);
#pragma unroll
                    for (int j = 0; j < 4; ++j) {
                        int lr = m * 16 + (lane >> 4) * 4 + j;
                        tl[lr * LROW + lc] = acc[m][n][j];
                    }
                }
        }
        __syncthreads();
#pragma unroll
        for (int it = 0; it < 8; ++it) {
            int lrow = it * 8 + trow8;
            int orow = row0 + half * 64 + lrow;
            float se = 0.f;
            float4 v = *(const float4*)&tl[lrow * LROW + c4 * 4];
            if (cvalid) {
                size_t o = (size_t)orow * C_COLS + col0 + c4 * 4;
                *(float4*)&cosm[o] = v;
                float4 lg = make_float4(scale * v.x, scale * v.y, scale * v.z,
                                        scale * v.w);
                *(float4*)&logits[o] = lg;
                se = __expf(lg.x) + __expf(lg.y) + __expf(lg.z) + __expf(lg.w);
            }
#pragma unroll
            for (int off = 1; off < 32; off <<= 1) se += __shfl_xor(se, off);
            if (c4 == 0) atomicAdd(&rowsum[orow], se);
        }
        __syncthreads();
    }
}

// ---------------------------------------------------------------------------
// Exact f32 recompute of cos_gt for each row (one wave per row, 4 rows/block):
// cg = <feat[row], weights[lbl]> / (||feat[row]|| * ||weights[lbl]||).
// Patches cosm gt column, writes gt logit via the cancellation-free identity
// pi/(2*theta) - 1 == asin(cg)/acos(cg) for cg > 0. Writes pgt/bvals.
// ---------------------------------------------------------------------------
__global__ __launch_bounds__(256) void gt_fix_kernel(
    const float* __restrict__ feat, const float* __restrict__ weights,
    const int* __restrict__ label, const float* __restrict__ rowsum,
    float* __restrict__ cosm, float* __restrict__ logits,
    float* __restrict__ pgt, float* __restrict__ bvals, float scale) {
    int row = blockIdx.x * 4 + (threadIdx.x >> 6);
    int lane = threadIdx.x & 63;
    if (row >= B_ROWS) return;
    int lbl = label[row];
    const float4* f4 = (const float4*)(feat + (size_t)row * D_DIM);
    const float4* w4 = (const float4*)(weights + (size_t)lbl * D_DIM);
    float ff = 0.f, ww = 0.f, fw = 0.f;
#pragma unroll
    for (int i = 0; i < 2; ++i) {
        float4 a = f4[lane + i * 64];
        float4 b = w4[lane + i * 64];
        ff += a.x * a.x + a.y * a.y + a.z * a.z + a.w * a.w;
        ww += b.x * b.x + b.y * b.y + b.z * b.z + b.w * b.w;
        fw += a.x * b.x + a.y * b.y + a.z * b.z + a.w * b.w;
    }
#pragma unroll
    for (int off = 32; off > 0; off >>= 1) {
        ff += __shfl_xor(ff, off);
        ww += __shfl_xor(ww, off);
        fw += __shfl_xor(fw, off);
    }
    if (lane == 0) {
        float cg = fw / (sqrtf(ff) * sqrtf(ww));
        float S = rowsum[row];
        float e = expf(scale * cg);
        float p = e / S;
        float Bv = S - e;  // == exp(logit_gt)*(1/p - 1) exactly
        const float PI = 3.14159265358979323846f;
        float marg;
        if (cg > 0.f) {
            marg = asinf(cg) / acosf(cg);  // == pi/(2*theta)-1, no cancellation
        } else {
            float dth = 0.5f * PI - 0.01f;
            marg = PI / (2.0f * dth) - 1.0f;
        }
        size_t o = (size_t)row * C_COLS + lbl;
        cosm[o] = cg;
        logits[o] = logf(Bv * marg);
        pgt[row] = p;
        bvals[row] = Bv;
    }
}

// ---------------------------------------------------------------------------
// Final scalar reductions, one block of 256.
// ---------------------------------------------------------------------------
__global__ __launch_bounds__(256) void finalize_kernel(const float* __restrict__ pgt,
                                                       const float* __restrict__ bvals,
                                                       float* __restrict__ tail,
                                                       float scale) {
    int tid = threadIdx.x;
    float s = 0.f, mn = 1e30f, mx = -1e30f, sb = 0.f;
    for (int i = tid; i < B_ROWS; i += 256) {
        float p = pgt[i];
        s += p;
        mn = fminf(mn, p);
        mx = fmaxf(mx, p);
        sb += bvals[i];
    }
#pragma unroll
    for (int off = 32; off > 0; off >>= 1) {
        s += __shfl_down(s, off);
        mn = fminf(mn, __shfl_down(mn, off));
        mx = fmaxf(mx, __shfl_down(mx, off));
        sb += __shfl_down(sb, off);
    }
    __shared__ float rs[4], rmn[4], rmx[4], rsb[4];
    int wave = tid >> 6;
    if ((tid & 63) == 0) { rs[wave] = s; rmn[wave] = mn; rmx[wave] = mx; rsb[wave] = sb; }
    __syncthreads();
    if (tid == 0) {
        float S = 0.f, MN = 1e30f, MX = -1e30f, SB = 0.f;
        for (int ww = 0; ww < 4; ++ww) {
            S += rs[ww]; MN = fminf(MN, rmn[ww]); MX = fmaxf(MX, rmx[ww]); SB += rsb[ww];
        }
        const float PI = 3.14159265358979323846f;
        tail[0] = S / (float)B_ROWS;
        tail[1] = MN;
        tail[2] = MX;
        float meanB = SB / (float)B_ROWS;
        tail[3] = acosf(logf(meanB / (float)(C_COLS - 1)) / scale) / PI * 180.0f;
        tail[4] = 0.0f;
        tail[5] = 0.0f;
    }
}

// ---------------------------------------------------------------------------
extern "C" void kernel_launch(void* const* d_in, const int* in_sizes, int n_in,
                              void* d_out, int out_size, void* d_ws, size_t ws_size,
                              hipStream_t stream) {
    const float* feat = (const float*)d_in[0];
    const int* label = (const int*)d_in[1];
    const float* weights = (const float*)d_in[2];

    float* out = (float*)d_out;
    float* cos_out = out;
    float* logits_out = out + (size_t)B_ROWS * C_COLS;
    float* tail = out + (size_t)2 * B_ROWS * C_COLS;

    double scale_d = std::sqrt(2.0) * std::log((double)(C_COLS - 1));
    float scale = (float)scale_d;

    const size_t fsz = (size_t)B_ROWS * D_DIM * sizeof(__hip_bfloat16);  // 2 MB
    const size_t wsz = (size_t)WPAD * D_DIM * sizeof(__hip_bfloat16);    // 10.875 MB
    char* wsb = (char*)d_ws;
    __hip_bfloat16* fhi = (__hip_bfloat16*)wsb;
    __hip_bfloat16* whi = (__hip_bfloat16*)(wsb + fsz);
    float* rowsum = (float*)(wsb + fsz + wsz);
    float* pgt = rowsum + B_ROWS;
    float* bv = pgt + B_ROWS;

    normcast_kernel<<<(B_ROWS + WPAD) / 4, 256, 0, stream>>>(feat, weights, fhi, whi,
                                                             rowsum);

    dim3 grid(WPAD / BN, B_ROWS / BM);  // 83 x 16 = 1328
    gemm_bf16_kernel<<<grid, 256, 0, stream>>>(fhi, whi, cos_out, logits_out, rowsum,
                                               scale);

    gt_fix_kernel<<<B_ROWS / 4, 256, 0, stream>>>(feat, weights, label, rowsum, cos_out,
                                                  logits_out, pgt, bv, scale);
    finalize_kernel<<<1, 256, 0, stream>>>(pgt, bv, tail, scale);
}